// Round 1
// baseline (426.973 us; speedup 1.0000x reference)
//
#include <hip/hip_runtime.h>
#include <cstdint>

#define N_PRED 1200
#define M_TGT  400
#define KDIM   25600   // 160*160
#define NCLS   81

typedef __attribute__((ext_vector_type(8))) short bf16x8;
typedef __attribute__((ext_vector_type(4))) float f32x4;

__device__ __forceinline__ ushort f2bf(float f) {
  union { float f; uint32_t u; } v; v.f = f;
  uint32_t u = v.u + 0x7fffu + ((v.u >> 16) & 1u);
  return (ushort)(u >> 16);
}

__device__ __forceinline__ float sigf(float x) {
  return 1.f / (1.f + __expf(-x));
}

// ---------------- resize: tgt_masks [400,256,256] -> T bf16 [400,25600], tsum[400] ----
// jax.image.resize bilinear, antialias=True: scale=160/256=0.625, inv=1.6,
// sample s=(o+0.5)*1.6-0.5, triangle kernel stretched by 1.6, weights normalized per output.
__global__ void resize_kernel(const float* __restrict__ tm, ushort* __restrict__ T,
                              float* __restrict__ tsum) {
  int m = blockIdx.x;
  int p = blockIdx.y * 256 + threadIdx.x;   // 0..25599
  int y = p / 160;
  int x = p - y * 160;

  float wy[4], wx[4];
  int jy0, jx0;
  {
    float s = (y + 0.5f) * 1.6f - 0.5f;
    jy0 = (int)ceilf(s - 1.6f);
    float ws = 0.f;
#pragma unroll
    for (int a = 0; a < 4; ++a) {
      int j = jy0 + a;
      float w = fmaxf(0.f, 1.f - fabsf((float)j - s) * 0.625f);
      if (j < 0 || j > 255) w = 0.f;
      wy[a] = w; ws += w;
    }
    float inv = 1.f / ws;
#pragma unroll
    for (int a = 0; a < 4; ++a) wy[a] *= inv;
  }
  {
    float s = (x + 0.5f) * 1.6f - 0.5f;
    jx0 = (int)ceilf(s - 1.6f);
    float ws = 0.f;
#pragma unroll
    for (int b = 0; b < 4; ++b) {
      int j = jx0 + b;
      float w = fmaxf(0.f, 1.f - fabsf((float)j - s) * 0.625f);
      if (j < 0 || j > 255) w = 0.f;
      wx[b] = w; ws += w;
    }
    float inv = 1.f / ws;
#pragma unroll
    for (int b = 0; b < 4; ++b) wx[b] *= inv;
  }

  const float* base = tm + (size_t)m * 65536;
  float acc = 0.f;
#pragma unroll
  for (int a = 0; a < 4; ++a) {
    int jy = min(max(jy0 + a, 0), 255);
    float wya = wy[a];
#pragma unroll
    for (int b = 0; b < 4; ++b) {
      int jx = min(max(jx0 + b, 0), 255);
      acc += wya * wx[b] * base[jy * 256 + jx];
    }
  }
  T[(size_t)m * KDIM + p] = f2bf(acc);

  // block-sum of the f32 resized values -> tsum[m]
  float v = acc;
#pragma unroll
  for (int o = 32; o > 0; o >>= 1) v += __shfl_down(v, o, 64);
  __shared__ float red[4];
  int wid = threadIdx.x >> 6;
  if ((threadIdx.x & 63) == 0) red[wid] = v;
  __syncthreads();
  if (threadIdx.x == 0) atomicAdd(&tsum[m], red[0] + red[1] + red[2] + red[3]);
}

// ---------------- softmax probs [1200,81] ----------------
__global__ void probs_kernel(const float* __restrict__ logits, float* __restrict__ probs) {
  int n = blockIdx.x;
  int l = threadIdx.x;            // 0..63, one wave
  const float* row = logits + n * NCLS;
  float v0 = row[l];
  bool has2 = (l + 64) < NCLS;
  float v1 = has2 ? row[l + 64] : -3.4e38f;
  float mx = fmaxf(v0, v1);
#pragma unroll
  for (int o = 1; o < 64; o <<= 1) mx = fmaxf(mx, __shfl_xor(mx, o, 64));
  float e0 = expf(v0 - mx);
  float e1 = has2 ? expf(v1 - mx) : 0.f;
  float s = e0 + e1;
#pragma unroll
  for (int o = 1; o < 64; o <<= 1) s += __shfl_xor(s, o, 64);
  float inv = 1.f / s;
  probs[n * NCLS + l] = e0 * inv;
  if (has2) probs[n * NCLS + l + 64] = e1 * inv;
}

// ---------------- row stats over pred_masks: S[n] = sum log_sigmoid(-x), sump[n] = sum sigmoid(x) ----
__global__ void stats_kernel(const float* __restrict__ pm, float* __restrict__ S,
                             float* __restrict__ sump) {
  int n = blockIdx.x;
  const float4* row = reinterpret_cast<const float4*>(pm + (size_t)n * KDIM);
  float ssp = 0.f, sp = 0.f;
  for (int i = threadIdx.x; i < KDIM / 4; i += 256) {
    float4 v = row[i];
    float xs[4] = {v.x, v.y, v.z, v.w};
#pragma unroll
    for (int j = 0; j < 4; ++j) {
      float x = xs[j];
      float e = __expf(-fabsf(x));
      float inv1pe = 1.f / (1.f + e);
      sp += (x >= 0.f) ? inv1pe : e * inv1pe;          // sigmoid
      ssp += fmaxf(x, 0.f) + log1pf(e);                // softplus(x)
    }
  }
#pragma unroll
  for (int o = 32; o > 0; o >>= 1) {
    ssp += __shfl_down(ssp, o, 64);
    sp  += __shfl_down(sp, o, 64);
  }
  __shared__ float red[8];
  int wid = threadIdx.x >> 6;
  if ((threadIdx.x & 63) == 0) { red[wid] = ssp; red[4 + wid] = sp; }
  __syncthreads();
  if (threadIdx.x == 0) {
    S[n]    = -(red[0] + red[1] + red[2] + red[3]);    // sum log_sigmoid(-x) = -sum softplus(x)
    sump[n] = red[4] + red[5] + red[6] + red[7];
  }
}

// ---------------- dual GEMM: A1 = x . t^T, A2 = sigmoid(x) . t^T ----------------
// 64x64 tile, BK=32, 4 waves, each wave 32x32 via 2x2 mfma_f32_16x16x32_bf16, split-K.
__device__ __forceinline__ bf16x8 load_frag(const ushort* p) {
  union { ushort4 u[2]; bf16x8 f; } fr;
  fr.u[0] = *reinterpret_cast<const ushort4*>(p);
  fr.u[1] = *reinterpret_cast<const ushort4*>(p + 4);
  return fr.f;
}

__global__ __launch_bounds__(256) void gemm_kernel(
    const float* __restrict__ pm, const ushort* __restrict__ T,
    float* __restrict__ part1, float* __restrict__ part2, int k_per) {
  __shared__ ushort Ax[64][40];   // pad 32->40 shorts: 80B row stride, ~2-way banks on b64
  __shared__ ushort Ap[64][40];
  __shared__ ushort Bs[64][40];

  int n0 = blockIdx.x * 64;
  int m0 = blockIdx.y * 64;
  int kz = blockIdx.z;
  int k_begin = kz * k_per;

  int t = threadIdx.x;
  int r = t >> 2;                  // staging row 0..63
  int q = t & 3;                   // 8-float chunk 0..3
  bool a_ok = (n0 + r) < N_PRED;
  bool b_ok = (m0 + r) < M_TGT;
  const float*  pA = pm + (size_t)(n0 + r) * KDIM + k_begin + q * 8;
  const ushort* pB = T  + (size_t)(m0 + r) * KDIM + k_begin + q * 8;

  int lane = t & 63;
  int w = t >> 6;
  int wr = (w >> 1) * 32;          // wave row offset in tile
  int wc = (w & 1) * 32;           // wave col offset
  int lrow = lane & 15;
  int kc = (lane >> 4) * 8;        // k-chunk within BK=32

  f32x4 zero = {0.f, 0.f, 0.f, 0.f};
  f32x4 acc1[2][2] = {{zero, zero}, {zero, zero}};
  f32x4 acc2[2][2] = {{zero, zero}, {zero, zero}};

  int steps = k_per / 32;
  for (int kt = 0; kt < steps; ++kt) {
    __syncthreads();
    // ---- stage A (f32 -> bf16 x and p=sigmoid(x)) and B (bf16 t) ----
    float4 f0 = {0.f,0.f,0.f,0.f}, f1 = {0.f,0.f,0.f,0.f};
    if (a_ok) {
      f0 = *reinterpret_cast<const float4*>(pA);
      f1 = *reinterpret_cast<const float4*>(pA + 4);
    }
    pA += 32;
    ushort4 xa, xb, pa, pb4;
    xa.x = f2bf(f0.x); xa.y = f2bf(f0.y); xa.z = f2bf(f0.z); xa.w = f2bf(f0.w);
    xb.x = f2bf(f1.x); xb.y = f2bf(f1.y); xb.z = f2bf(f1.z); xb.w = f2bf(f1.w);
    pa.x = f2bf(sigf(f0.x)); pa.y = f2bf(sigf(f0.y)); pa.z = f2bf(sigf(f0.z)); pa.w = f2bf(sigf(f0.w));
    pb4.x = f2bf(sigf(f1.x)); pb4.y = f2bf(sigf(f1.y)); pb4.z = f2bf(sigf(f1.z)); pb4.w = f2bf(sigf(f1.w));
    *reinterpret_cast<ushort4*>(&Ax[r][q * 8])     = xa;
    *reinterpret_cast<ushort4*>(&Ax[r][q * 8 + 4]) = xb;
    *reinterpret_cast<ushort4*>(&Ap[r][q * 8])     = pa;
    *reinterpret_cast<ushort4*>(&Ap[r][q * 8 + 4]) = pb4;
    union { uint4 u; ushort4 s[2]; } bv;
    bv.u = make_uint4(0, 0, 0, 0);
    if (b_ok) bv.u = *reinterpret_cast<const uint4*>(pB);
    pB += 32;
    *reinterpret_cast<ushort4*>(&Bs[r][q * 8])     = bv.s[0];
    *reinterpret_cast<ushort4*>(&Bs[r][q * 8 + 4]) = bv.s[1];
    __syncthreads();

    // ---- fragments + MFMA ----
    bf16x8 ax[2], ap[2], bb[2];
#pragma unroll
    for (int i = 0; i < 2; ++i) {
      ax[i] = load_frag(&Ax[wr + i * 16 + lrow][kc]);
      ap[i] = load_frag(&Ap[wr + i * 16 + lrow][kc]);
      bb[i] = load_frag(&Bs[wc + i * 16 + lrow][kc]);
    }
#pragma unroll
    for (int i = 0; i < 2; ++i)
#pragma unroll
      for (int j = 0; j < 2; ++j) {
        acc1[i][j] = __builtin_amdgcn_mfma_f32_16x16x32_bf16(ax[i], bb[j], acc1[i][j], 0, 0, 0);
        acc2[i][j] = __builtin_amdgcn_mfma_f32_16x16x32_bf16(ap[i], bb[j], acc2[i][j], 0, 0, 0);
      }
  }

  // ---- store partials: C/D layout col=lane&15, row=(lane>>4)*4+rr ----
  int rowb = (lane >> 4) * 4;
  int col = lane & 15;
#pragma unroll
  for (int i = 0; i < 2; ++i)
#pragma unroll
    for (int j = 0; j < 2; ++j)
#pragma unroll
      for (int rr = 0; rr < 4; ++rr) {
        int gn = n0 + wr + i * 16 + rowb + rr;
        int gm = m0 + wc + j * 16 + col;
        if (gn < N_PRED && gm < M_TGT) {
          size_t o = ((size_t)kz * N_PRED + gn) * M_TGT + gm;
          part1[o] = acc1[i][j][rr];
          part2[o] = acc2[i][j][rr];
        }
      }
}

// ---------------- final combine ----------------
__global__ void combine_kernel(const float* __restrict__ part1, const float* __restrict__ part2,
                               const float* __restrict__ S, const float* __restrict__ sump,
                               const float* __restrict__ tsum, const float* __restrict__ probs,
                               const float* __restrict__ pboxes, const float* __restrict__ tboxes,
                               const int* __restrict__ tids, float* __restrict__ out, int KZ) {
  int idx = blockIdx.x * 256 + threadIdx.x;   // < 480000
  int n = idx / M_TGT;
  int m = idx - n * M_TGT;

  float A1 = 0.f, A2 = 0.f;
  for (int kz = 0; kz < KZ; ++kz) {
    A1 += part1[(size_t)kz * (N_PRED * M_TGT) + idx];
    A2 += part2[(size_t)kz * (N_PRED * M_TGT) + idx];
  }
  float cm = -(A1 + S[n]) * (1.0f / (float)KDIM);
  float cd = 1.f - (2.f * A2 + 1e-5f) / (sump[n] + tsum[m] + 1e-5f);
  float cc = -probs[n * NCLS + tids[m]];

  float4 pb = reinterpret_cast<const float4*>(pboxes)[n];
  float4 tb = reinterpret_cast<const float4*>(tboxes)[m];
  float l1 = fabsf(pb.x - tb.x) + fabsf(pb.y - tb.y) + fabsf(pb.z - tb.z) + fabsf(pb.w - tb.w);
  float px1 = pb.x - 0.5f * pb.z, py1 = pb.y - 0.5f * pb.w;
  float px2 = pb.x + 0.5f * pb.z, py2 = pb.y + 0.5f * pb.w;
  float tx1 = tb.x - 0.5f * tb.z, ty1 = tb.y - 0.5f * tb.w;
  float tx2 = tb.x + 0.5f * tb.z, ty2 = tb.y + 0.5f * tb.w;
  float a1 = (px2 - px1) * (py2 - py1);
  float a2 = (tx2 - tx1) * (ty2 - ty1);
  float iw = fmaxf(fminf(px2, tx2) - fmaxf(px1, tx1), 0.f);
  float ih = fmaxf(fminf(py2, ty2) - fmaxf(py1, ty1), 0.f);
  float inter = iw * ih;
  float uni = a1 + a2 - inter;
  float iou = inter / uni;
  float ew = fmaxf(fmaxf(px2, tx2) - fminf(px1, tx1), 0.f);
  float eh = fmaxf(fmaxf(py2, ty2) - fminf(py1, ty1), 0.f);
  float ae = ew * eh;
  float giou = iou - (ae - uni) / ae;

  out[idx] = 5.f * l1 + 2.f * (-giou) + 2.f * cc + 5.f * cm + 5.f * cd;
}

extern "C" void kernel_launch(void* const* d_in, const int* in_sizes, int n_in,
                              void* d_out, int out_size, void* d_ws, size_t ws_size,
                              hipStream_t stream) {
  const float* logits = (const float*)d_in[0];
  const float* pboxes = (const float*)d_in[1];
  const float* pmasks = (const float*)d_in[2];
  const float* tboxes = (const float*)d_in[3];
  const float* tmasks = (const float*)d_in[4];
  const int*   tids   = (const int*)d_in[5];
  float* out = (float*)d_out;
  char* ws = (char*)d_ws;

  // workspace layout
  ushort* T     = (ushort*)ws;                       // 400*25600*2 = 20,480,000
  float*  probs = (float*)(ws + 20480000);           // 1200*81*4   =    388,800
  float*  S     = (float*)(ws + 20868800);           // 1200*4
  float*  sump  = (float*)(ws + 20873600);           // 1200*4
  float*  tsum  = (float*)(ws + 20878400);           // 400*4
  float*  part1 = (float*)(ws + 20880000);

  size_t need8 = 20880000ull + 2ull * 8 * 480000 * 4;
  int KZ = (ws_size >= need8) ? 8 : 1;
  float* part2 = part1 + (size_t)KZ * 480000;

  hipMemsetAsync(tsum, 0, M_TGT * sizeof(float), stream);
  resize_kernel<<<dim3(M_TGT, 100), 256, 0, stream>>>(tmasks, T, tsum);
  probs_kernel<<<N_PRED, 64, 0, stream>>>(logits, probs);
  stats_kernel<<<N_PRED, 256, 0, stream>>>(pmasks, S, sump);
  gemm_kernel<<<dim3(19, 7, KZ), 256, 0, stream>>>(pmasks, T, part1, part2, KDIM / KZ);
  combine_kernel<<<1875, 256, 0, stream>>>(part1, part2, S, sump, tsum, probs,
                                           pboxes, tboxes, tids, out, KZ);
}

// Round 2
// 343.783 us; speedup vs baseline: 1.2420x; 1.2420x over previous
//
#include <hip/hip_runtime.h>
#include <cstdint>

#define N_PRED 1200
#define M_TGT  400
#define KDIM   25600   // 160*160
#define NCLS   81

typedef __attribute__((ext_vector_type(8))) short bf16x8;
typedef __attribute__((ext_vector_type(4))) float f32x4;

__device__ __forceinline__ ushort f2bf(float f) {
  union { float f; uint32_t u; } v; v.f = f;
  uint32_t u = v.u + 0x7fffu + ((v.u >> 16) & 1u);
  return (ushort)(u >> 16);
}

__device__ __forceinline__ float sigf(float x) {
  return 1.f / (1.f + __expf(-x));
}

__device__ __forceinline__ void gll16(const void* g, void* l) {
  __builtin_amdgcn_global_load_lds(
      (const __attribute__((address_space(1))) void*)g,
      (__attribute__((address_space(3))) void*)l, 16, 0, 0);
}

// =====================================================================
// NEW PATH
// =====================================================================

// Convert pred_masks f32 -> X_swz (bf16 logits), P_swz (bf16 sigmoid), fused row
// stats. Swizzled tile-blocked layout: X_swz[ntile][kt][row*8 + (q^(row&7))][8]
// (ntile: 128 rows of n; kt: 64-wide k step; q: 8-short chunk within the k step).
__global__ void convert_kernel(const float* __restrict__ pm, ushort* __restrict__ X,
                               ushort* __restrict__ P, float* __restrict__ S,
                               float* __restrict__ sump) {
  int n = blockIdx.x;            // 0..1279 (1200..1279 = zero pad rows)
  int t = threadIdx.x;
  int ntile = n >> 7, row = n & 127, r7 = row & 7;

  if (n >= N_PRED) {
    ushort4 z = {0, 0, 0, 0};
    for (int i = t; i < 3200; i += 256) {
      int kt = i >> 3, q = i & 7, slot = q ^ r7;
      size_t a = (((size_t)(ntile * 400 + kt)) << 13) + (size_t)(row * 8 + slot) * 8;
      *reinterpret_cast<ushort4*>(&X[a]) = z;
      *reinterpret_cast<ushort4*>(&X[a + 4]) = z;
      *reinterpret_cast<ushort4*>(&P[a]) = z;
      *reinterpret_cast<ushort4*>(&P[a + 4]) = z;
    }
    return;
  }

  const float4* src = reinterpret_cast<const float4*>(pm + (size_t)n * KDIM);
  float ssp = 0.f, sp = 0.f;
  for (int i = t; i < 3200; i += 256) {
    float4 f0 = src[i * 2];
    float4 f1 = src[i * 2 + 1];
    float xs[8] = {f0.x, f0.y, f0.z, f0.w, f1.x, f1.y, f1.z, f1.w};
    ushort xv[8], pv[8];
#pragma unroll
    for (int j = 0; j < 8; ++j) {
      float x = xs[j];
      float e = __expf(-fabsf(x));
      float inv = 1.f / (1.f + e);
      float sg = (x >= 0.f) ? inv : e * inv;
      sp += sg;
      ssp += fmaxf(x, 0.f) + log1pf(e);
      xv[j] = f2bf(x);
      pv[j] = f2bf(sg);
    }
    int kt = i >> 3, q = i & 7, slot = q ^ r7;
    size_t a = (((size_t)(ntile * 400 + kt)) << 13) + (size_t)(row * 8 + slot) * 8;
    *reinterpret_cast<ushort4*>(&X[a])     = make_ushort4(xv[0], xv[1], xv[2], xv[3]);
    *reinterpret_cast<ushort4*>(&X[a + 4]) = make_ushort4(xv[4], xv[5], xv[6], xv[7]);
    *reinterpret_cast<ushort4*>(&P[a])     = make_ushort4(pv[0], pv[1], pv[2], pv[3]);
    *reinterpret_cast<ushort4*>(&P[a + 4]) = make_ushort4(pv[4], pv[5], pv[6], pv[7]);
  }
#pragma unroll
  for (int o = 32; o > 0; o >>= 1) {
    ssp += __shfl_down(ssp, o, 64);
    sp  += __shfl_down(sp, o, 64);
  }
  __shared__ float red[8];
  int wid = t >> 6;
  if ((t & 63) == 0) { red[wid] = ssp; red[4 + wid] = sp; }
  __syncthreads();
  if (t == 0) {
    S[n]    = -(red[0] + red[1] + red[2] + red[3]);
    sump[n] = red[4] + red[5] + red[6] + red[7];
  }
}

// Resize tgt_masks [400,256,256] -> T_swz [mtile(5)][kt(400)][row*8+(q^(row&7))][8]
// One output row per block: vertical pass (256 threads) into LDS, horizontal pass
// (20 threads x 8 outputs) with 16B swizzled stores. tsum accumulated per m.
__global__ void resize_swz(const float* __restrict__ tm, ushort* __restrict__ T,
                           float* __restrict__ tsum) {
  int m = blockIdx.x, y = blockIdx.y;
  int t = threadIdx.x;
  int mtile = m / 80, trow = m % 80;

  float s = (y + 0.5f) * 1.6f - 0.5f;
  int jy0 = (int)ceilf(s - 1.6f);
  float wy[4]; float wsum = 0.f;
#pragma unroll
  for (int a = 0; a < 4; ++a) {
    int j = jy0 + a;
    float w = fmaxf(0.f, 1.f - fabsf((float)j - s) * 0.625f);
    if (j < 0 || j > 255) w = 0.f;
    wy[a] = w; wsum += w;
  }
  float winv = 1.f / wsum;
#pragma unroll
  for (int a = 0; a < 4; ++a) wy[a] *= winv;

  const float* base = tm + (size_t)m * 65536;
  float v = 0.f;
#pragma unroll
  for (int a = 0; a < 4; ++a) {
    int jy = min(max(jy0 + a, 0), 255);
    v += wy[a] * base[jy * 256 + t];
  }
  __shared__ float vrow[256];
  vrow[t] = v;
  __syncthreads();

  if (t < 64) {
    float msum = 0.f;
    if (t < 20) {
      float o[8];
#pragma unroll
      for (int j = 0; j < 8; ++j) {
        int x = t * 8 + j;
        float sx = (x + 0.5f) * 1.6f - 0.5f;
        int jx0 = (int)ceilf(sx - 1.6f);
        float w0 = 0.f, h = 0.f;
#pragma unroll
        for (int b = 0; b < 4; ++b) {
          int jj = jx0 + b;
          float w = fmaxf(0.f, 1.f - fabsf((float)jj - sx) * 0.625f);
          if (jj < 0 || jj > 255) w = 0.f;
          w0 += w;
          h += w * vrow[min(max(jj, 0), 255)];
        }
        h /= w0;
        o[j] = h; msum += h;
      }
      int p0 = y * 160 + t * 8;
      int kt = p0 >> 6, q = (p0 >> 3) & 7, slot = q ^ (trow & 7);
      size_t a = (size_t)(mtile * 400 + kt) * 5120 + (size_t)(trow * 8 + slot) * 8;
      *reinterpret_cast<ushort4*>(&T[a]) =
          make_ushort4(f2bf(o[0]), f2bf(o[1]), f2bf(o[2]), f2bf(o[3]));
      *reinterpret_cast<ushort4*>(&T[a + 4]) =
          make_ushort4(f2bf(o[4]), f2bf(o[5]), f2bf(o[6]), f2bf(o[7]));
    }
#pragma unroll
    for (int o2 = 32; o2 > 0; o2 >>= 1) msum += __shfl_down(msum, o2, 64);
    if (t == 0) atomicAdd(&tsum[m], msum);
  }
}

// Dual GEMM from pre-swizzled bf16 operands. BM=128, BN=80, BK=64, 4 waves,
// each wave 32 rows x 80 cols (2x5 frags x 2 accumulator sets). Single-buffer
// LDS (43 KB), global_load_lds(16B) staging from contiguous pre-swizzled blocks.
__global__ __launch_bounds__(256) void gemm_swz(
    const ushort* __restrict__ Xg, const ushort* __restrict__ Pg,
    const ushort* __restrict__ Tg, float* __restrict__ part1,
    float* __restrict__ part2, int steps) {
  __shared__ ushort lds[21504];   // X[0..8191] P[8192..16383] T[16384..21503]

  int bn = blockIdx.x, bm = blockIdx.y, kz = blockIdx.z;
  int t = threadIdx.x, lane = t & 63, w = t >> 6;
  int wbase = t & 0xFFC0;        // t - lane
  int kt0 = kz * steps;

  const ushort* srcX = Xg + (((size_t)(bn * 400 + kt0)) << 13);
  const ushort* srcP = Pg + (((size_t)(bn * 400 + kt0)) << 13);
  const ushort* srcT = Tg + (size_t)(bm * 400 + kt0) * 5120;

  int wr = w * 32, lrow = lane & 15, kq = lane >> 4;
  int r0 = wr + lrow, r1 = r0 + 16;
  int r07 = r0 & 7;              // == r1 & 7

  f32x4 z = {0.f, 0.f, 0.f, 0.f};
  f32x4 acc1[2][5], acc2[2][5];
#pragma unroll
  for (int i = 0; i < 2; ++i)
#pragma unroll
    for (int j = 0; j < 5; ++j) { acc1[i][j] = z; acc2[i][j] = z; }

  for (int st = 0; st < steps; ++st) {
    // ---- stage 43 KB: 4+4+2.5 global_load_lds_dwordx4 per thread ----
#pragma unroll
    for (int i = 0; i < 4; ++i)
      gll16(srcX + (size_t)(i * 256 + t) * 8, &lds[(i * 256 + wbase) * 8]);
#pragma unroll
    for (int i = 0; i < 4; ++i)
      gll16(srcP + (size_t)(i * 256 + t) * 8, &lds[8192 + (i * 256 + wbase) * 8]);
    gll16(srcT + (size_t)t * 8,         &lds[16384 + wbase * 8]);
    gll16(srcT + (size_t)(256 + t) * 8, &lds[16384 + (256 + wbase) * 8]);
    if (t < 128)
      gll16(srcT + (size_t)(512 + t) * 8, &lds[16384 + (512 + wbase) * 8]);
    __syncthreads();   // compiler drains vmcnt(0) before s_barrier

#pragma unroll
    for (int h = 0; h < 2; ++h) {
      int q = h * 4 + kq;
      int sa = (q ^ r07) << 3;
      bf16x8 ax0 = *reinterpret_cast<const bf16x8*>(&lds[r0 * 64 + sa]);
      bf16x8 ax1 = *reinterpret_cast<const bf16x8*>(&lds[r1 * 64 + sa]);
      bf16x8 ap0 = *reinterpret_cast<const bf16x8*>(&lds[8192 + r0 * 64 + sa]);
      bf16x8 ap1 = *reinterpret_cast<const bf16x8*>(&lds[8192 + r1 * 64 + sa]);
      bf16x8 bt[5];
#pragma unroll
      for (int j = 0; j < 5; ++j) {
        int tr = j * 16 + lrow;
        bt[j] = *reinterpret_cast<const bf16x8*>(
            &lds[16384 + tr * 64 + ((q ^ (tr & 7)) << 3)]);
      }
#pragma unroll
      for (int j = 0; j < 5; ++j) {
        acc1[0][j] = __builtin_amdgcn_mfma_f32_16x16x32_bf16(ax0, bt[j], acc1[0][j], 0, 0, 0);
        acc1[1][j] = __builtin_amdgcn_mfma_f32_16x16x32_bf16(ax1, bt[j], acc1[1][j], 0, 0, 0);
        acc2[0][j] = __builtin_amdgcn_mfma_f32_16x16x32_bf16(ap0, bt[j], acc2[0][j], 0, 0, 0);
        acc2[1][j] = __builtin_amdgcn_mfma_f32_16x16x32_bf16(ap1, bt[j], acc2[1][j], 0, 0, 0);
      }
    }
    __syncthreads();   // protect LDS before next stage
    srcX += 8192; srcP += 8192; srcT += 5120;
  }

  int rowb = (lane >> 4) * 4, col = lane & 15;
  int n0 = bn * 128 + wr;
#pragma unroll
  for (int i = 0; i < 2; ++i)
#pragma unroll
    for (int j = 0; j < 5; ++j)
#pragma unroll
      for (int rr = 0; rr < 4; ++rr) {
        int gn = n0 + i * 16 + rowb + rr;
        if (gn < N_PRED) {
          int gm = bm * 80 + j * 16 + col;
          size_t o = (size_t)kz * 480000 + (size_t)gn * 400 + gm;
          part1[o] = acc1[i][j][rr];
          part2[o] = acc2[i][j][rr];
        }
      }
}

// ---------------- softmax probs [1200,81] ----------------
__global__ void probs_kernel(const float* __restrict__ logits, float* __restrict__ probs) {
  int n = blockIdx.x;
  int l = threadIdx.x;
  const float* row = logits + n * NCLS;
  float v0 = row[l];
  bool has2 = (l + 64) < NCLS;
  float v1 = has2 ? row[l + 64] : -3.4e38f;
  float mx = fmaxf(v0, v1);
#pragma unroll
  for (int o = 1; o < 64; o <<= 1) mx = fmaxf(mx, __shfl_xor(mx, o, 64));
  float e0 = expf(v0 - mx);
  float e1 = has2 ? expf(v1 - mx) : 0.f;
  float sm = e0 + e1;
#pragma unroll
  for (int o = 1; o < 64; o <<= 1) sm += __shfl_xor(sm, o, 64);
  float inv = 1.f / sm;
  probs[n * NCLS + l] = e0 * inv;
  if (has2) probs[n * NCLS + l + 64] = e1 * inv;
}

// ---------------- final combine ----------------
__global__ void combine_kernel(const float* __restrict__ part1, const float* __restrict__ part2,
                               const float* __restrict__ S, const float* __restrict__ sump,
                               const float* __restrict__ tsum, const float* __restrict__ probs,
                               const float* __restrict__ pboxes, const float* __restrict__ tboxes,
                               const int* __restrict__ tids, float* __restrict__ out, int KZ) {
  int idx = blockIdx.x * 256 + threadIdx.x;
  int n = idx / M_TGT;
  int m = idx - n * M_TGT;

  float A1 = 0.f, A2 = 0.f;
  for (int kz = 0; kz < KZ; ++kz) {
    A1 += part1[(size_t)kz * 480000 + idx];
    A2 += part2[(size_t)kz * 480000 + idx];
  }
  float cm = -(A1 + S[n]) * (1.0f / (float)KDIM);
  float cd = 1.f - (2.f * A2 + 1e-5f) / (sump[n] + tsum[m] + 1e-5f);
  float cc = -probs[n * NCLS + tids[m]];

  float4 pb = reinterpret_cast<const float4*>(pboxes)[n];
  float4 tb = reinterpret_cast<const float4*>(tboxes)[m];
  float l1 = fabsf(pb.x - tb.x) + fabsf(pb.y - tb.y) + fabsf(pb.z - tb.z) + fabsf(pb.w - tb.w);
  float px1 = pb.x - 0.5f * pb.z, py1 = pb.y - 0.5f * pb.w;
  float px2 = pb.x + 0.5f * pb.z, py2 = pb.y + 0.5f * pb.w;
  float tx1 = tb.x - 0.5f * tb.z, ty1 = tb.y - 0.5f * tb.w;
  float tx2 = tb.x + 0.5f * tb.z, ty2 = tb.y + 0.5f * tb.w;
  float a1 = (px2 - px1) * (py2 - py1);
  float a2 = (tx2 - tx1) * (ty2 - ty1);
  float iw = fmaxf(fminf(px2, tx2) - fmaxf(px1, tx1), 0.f);
  float ih = fmaxf(fminf(py2, ty2) - fmaxf(py1, ty1), 0.f);
  float inter = iw * ih;
  float uni = a1 + a2 - inter;
  float iou = inter / uni;
  float ew = fmaxf(fmaxf(px2, tx2) - fminf(px1, tx1), 0.f);
  float eh = fmaxf(fmaxf(py2, ty2) - fminf(py1, ty1), 0.f);
  float ae = ew * eh;
  float giou = iou - (ae - uni) / ae;

  out[idx] = 5.f * l1 + 2.f * (-giou) + 2.f * cc + 5.f * cm + 5.f * cd;
}

// =====================================================================
// FALLBACK PATH (round-1 kernels, used only if ws_size too small)
// =====================================================================

__global__ void resize_lin(const float* __restrict__ tm, ushort* __restrict__ T,
                           float* __restrict__ tsum) {
  int m = blockIdx.x;
  int p = blockIdx.y * 256 + threadIdx.x;
  int y = p / 160;
  int x = p - y * 160;
  float wy[4], wx[4];
  int jy0, jx0;
  {
    float s = (y + 0.5f) * 1.6f - 0.5f;
    jy0 = (int)ceilf(s - 1.6f);
    float ws = 0.f;
#pragma unroll
    for (int a = 0; a < 4; ++a) {
      int j = jy0 + a;
      float w = fmaxf(0.f, 1.f - fabsf((float)j - s) * 0.625f);
      if (j < 0 || j > 255) w = 0.f;
      wy[a] = w; ws += w;
    }
    float inv = 1.f / ws;
#pragma unroll
    for (int a = 0; a < 4; ++a) wy[a] *= inv;
  }
  {
    float s = (x + 0.5f) * 1.6f - 0.5f;
    jx0 = (int)ceilf(s - 1.6f);
    float ws = 0.f;
#pragma unroll
    for (int b = 0; b < 4; ++b) {
      int j = jx0 + b;
      float w = fmaxf(0.f, 1.f - fabsf((float)j - s) * 0.625f);
      if (j < 0 || j > 255) w = 0.f;
      wx[b] = w; ws += w;
    }
    float inv = 1.f / ws;
#pragma unroll
    for (int b = 0; b < 4; ++b) wx[b] *= inv;
  }
  const float* base = tm + (size_t)m * 65536;
  float acc = 0.f;
#pragma unroll
  for (int a = 0; a < 4; ++a) {
    int jy = min(max(jy0 + a, 0), 255);
    float wya = wy[a];
#pragma unroll
    for (int b = 0; b < 4; ++b) {
      int jx = min(max(jx0 + b, 0), 255);
      acc += wya * wx[b] * base[jy * 256 + jx];
    }
  }
  T[(size_t)m * KDIM + p] = f2bf(acc);
  float v = acc;
#pragma unroll
  for (int o = 32; o > 0; o >>= 1) v += __shfl_down(v, o, 64);
  __shared__ float red[4];
  int wid = threadIdx.x >> 6;
  if ((threadIdx.x & 63) == 0) red[wid] = v;
  __syncthreads();
  if (threadIdx.x == 0) atomicAdd(&tsum[m], red[0] + red[1] + red[2] + red[3]);
}

__global__ void stats_kernel(const float* __restrict__ pm, float* __restrict__ S,
                             float* __restrict__ sump) {
  int n = blockIdx.x;
  const float4* row = reinterpret_cast<const float4*>(pm + (size_t)n * KDIM);
  float ssp = 0.f, sp = 0.f;
  for (int i = threadIdx.x; i < KDIM / 4; i += 256) {
    float4 v = row[i];
    float xs[4] = {v.x, v.y, v.z, v.w};
#pragma unroll
    for (int j = 0; j < 4; ++j) {
      float x = xs[j];
      float e = __expf(-fabsf(x));
      float inv1pe = 1.f / (1.f + e);
      sp += (x >= 0.f) ? inv1pe : e * inv1pe;
      ssp += fmaxf(x, 0.f) + log1pf(e);
    }
  }
#pragma unroll
  for (int o = 32; o > 0; o >>= 1) {
    ssp += __shfl_down(ssp, o, 64);
    sp  += __shfl_down(sp, o, 64);
  }
  __shared__ float red[8];
  int wid = threadIdx.x >> 6;
  if ((threadIdx.x & 63) == 0) { red[wid] = ssp; red[4 + wid] = sp; }
  __syncthreads();
  if (threadIdx.x == 0) {
    S[n]    = -(red[0] + red[1] + red[2] + red[3]);
    sump[n] = red[4] + red[5] + red[6] + red[7];
  }
}

__device__ __forceinline__ bf16x8 load_frag_lin(const ushort* p) {
  union { ushort4 u[2]; bf16x8 f; } fr;
  fr.u[0] = *reinterpret_cast<const ushort4*>(p);
  fr.u[1] = *reinterpret_cast<const ushort4*>(p + 4);
  return fr.f;
}

__global__ __launch_bounds__(256) void gemm_fused(
    const float* __restrict__ pm, const ushort* __restrict__ T,
    float* __restrict__ part1, float* __restrict__ part2, int k_per) {
  __shared__ ushort Ax[64][40];
  __shared__ ushort Ap[64][40];
  __shared__ ushort Bs[64][40];
  int n0 = blockIdx.x * 64;
  int m0 = blockIdx.y * 64;
  int kz = blockIdx.z;
  int k_begin = kz * k_per;
  int t = threadIdx.x;
  int r = t >> 2;
  int q = t & 3;
  bool a_ok = (n0 + r) < N_PRED;
  bool b_ok = (m0 + r) < M_TGT;
  const float*  pA = pm + (size_t)(n0 + r) * KDIM + k_begin + q * 8;
  const ushort* pB = T  + (size_t)(m0 + r) * KDIM + k_begin + q * 8;
  int lane = t & 63;
  int w = t >> 6;
  int wr = (w >> 1) * 32;
  int wc = (w & 1) * 32;
  int lrow = lane & 15;
  int kc = (lane >> 4) * 8;
  f32x4 zero = {0.f, 0.f, 0.f, 0.f};
  f32x4 acc1[2][2] = {{zero, zero}, {zero, zero}};
  f32x4 acc2[2][2] = {{zero, zero}, {zero, zero}};
  int steps = k_per / 32;
  for (int kt = 0; kt < steps; ++kt) {
    __syncthreads();
    float4 f0 = {0.f,0.f,0.f,0.f}, f1 = {0.f,0.f,0.f,0.f};
    if (a_ok) {
      f0 = *reinterpret_cast<const float4*>(pA);
      f1 = *reinterpret_cast<const float4*>(pA + 4);
    }
    pA += 32;
    ushort4 xa, xb, pa, pb4;
    xa.x = f2bf(f0.x); xa.y = f2bf(f0.y); xa.z = f2bf(f0.z); xa.w = f2bf(f0.w);
    xb.x = f2bf(f1.x); xb.y = f2bf(f1.y); xb.z = f2bf(f1.z); xb.w = f2bf(f1.w);
    pa.x = f2bf(sigf(f0.x)); pa.y = f2bf(sigf(f0.y)); pa.z = f2bf(sigf(f0.z)); pa.w = f2bf(sigf(f0.w));
    pb4.x = f2bf(sigf(f1.x)); pb4.y = f2bf(sigf(f1.y)); pb4.z = f2bf(sigf(f1.z)); pb4.w = f2bf(sigf(f1.w));
    *reinterpret_cast<ushort4*>(&Ax[r][q * 8])     = xa;
    *reinterpret_cast<ushort4*>(&Ax[r][q * 8 + 4]) = xb;
    *reinterpret_cast<ushort4*>(&Ap[r][q * 8])     = pa;
    *reinterpret_cast<ushort4*>(&Ap[r][q * 8 + 4]) = pb4;
    union { uint4 u; ushort4 s[2]; } bv;
    bv.u = make_uint4(0, 0, 0, 0);
    if (b_ok) bv.u = *reinterpret_cast<const uint4*>(pB);
    pB += 32;
    *reinterpret_cast<ushort4*>(&Bs[r][q * 8])     = bv.s[0];
    *reinterpret_cast<ushort4*>(&Bs[r][q * 8 + 4]) = bv.s[1];
    __syncthreads();
    bf16x8 ax[2], ap[2], bb[2];
#pragma unroll
    for (int i = 0; i < 2; ++i) {
      ax[i] = load_frag_lin(&Ax[wr + i * 16 + lrow][kc]);
      ap[i] = load_frag_lin(&Ap[wr + i * 16 + lrow][kc]);
      bb[i] = load_frag_lin(&Bs[wc + i * 16 + lrow][kc]);
    }
#pragma unroll
    for (int i = 0; i < 2; ++i)
#pragma unroll
      for (int j = 0; j < 2; ++j) {
        acc1[i][j] = __builtin_amdgcn_mfma_f32_16x16x32_bf16(ax[i], bb[j], acc1[i][j], 0, 0, 0);
        acc2[i][j] = __builtin_amdgcn_mfma_f32_16x16x32_bf16(ap[i], bb[j], acc2[i][j], 0, 0, 0);
      }
  }
  int rowb = (lane >> 4) * 4;
  int col = lane & 15;
#pragma unroll
  for (int i = 0; i < 2; ++i)
#pragma unroll
    for (int j = 0; j < 2; ++j)
#pragma unroll
      for (int rr = 0; rr < 4; ++rr) {
        int gn = n0 + wr + i * 16 + rowb + rr;
        int gm = m0 + wc + j * 16 + col;
        if (gn < N_PRED && gm < M_TGT) {
          size_t o = (size_t)kz * 480000 + (size_t)gn * 400 + gm;
          part1[o] = acc1[i][j][rr];
          part2[o] = acc2[i][j][rr];
        }
      }
}

// =====================================================================

extern "C" void kernel_launch(void* const* d_in, const int* in_sizes, int n_in,
                              void* d_out, int out_size, void* d_ws, size_t ws_size,
                              hipStream_t stream) {
  const float* logits = (const float*)d_in[0];
  const float* pboxes = (const float*)d_in[1];
  const float* pmasks = (const float*)d_in[2];
  const float* tboxes = (const float*)d_in[3];
  const float* tmasks = (const float*)d_in[4];
  const int*   tids   = (const int*)d_in[5];
  float* out = (float*)d_out;
  char* ws = (char*)d_ws;

  // new-path layout
  const size_t offX = 0;
  const size_t offP = 65536000;
  const size_t offT = 131072000;
  const size_t offProbs = 151552000;
  const size_t offS = 151940800;
  const size_t offSump = 151945600;
  const size_t offTsum = 151950400;
  const size_t offParts = 151952000;

  int KZ = 0;
  if      (ws_size >= offParts + 2ull * 16 * 480000 * 4) KZ = 16;
  else if (ws_size >= offParts + 2ull * 8  * 480000 * 4) KZ = 8;
  else if (ws_size >= offParts + 2ull * 4  * 480000 * 4) KZ = 4;
  else if (ws_size >= offParts + 2ull * 2  * 480000 * 4) KZ = 2;

  if (KZ > 0) {
    ushort* Xg   = (ushort*)(ws + offX);
    ushort* Pg   = (ushort*)(ws + offP);
    ushort* Tg   = (ushort*)(ws + offT);
    float* probs = (float*)(ws + offProbs);
    float* S     = (float*)(ws + offS);
    float* sump  = (float*)(ws + offSump);
    float* tsum  = (float*)(ws + offTsum);
    float* part1 = (float*)(ws + offParts);
    float* part2 = part1 + (size_t)KZ * 480000;

    hipMemsetAsync(tsum, 0, M_TGT * sizeof(float), stream);
    convert_kernel<<<1280, 256, 0, stream>>>(pmasks, Xg, Pg, S, sump);
    resize_swz<<<dim3(M_TGT, 160), 256, 0, stream>>>(tmasks, Tg, tsum);
    probs_kernel<<<N_PRED, 64, 0, stream>>>(logits, probs);
    gemm_swz<<<dim3(10, 5, KZ), 256, 0, stream>>>(Xg, Pg, Tg, part1, part2, 400 / KZ);
    combine_kernel<<<1875, 256, 0, stream>>>(part1, part2, S, sump, tsum, probs,
                                             pboxes, tboxes, tids, out, KZ);
  } else {
    // fallback (round-1 pipeline)
    ushort* T     = (ushort*)ws;
    float*  probs = (float*)(ws + 20480000);
    float*  S     = (float*)(ws + 20868800);
    float*  sump  = (float*)(ws + 20873600);
    float*  tsum  = (float*)(ws + 20878400);
    float*  part1 = (float*)(ws + 20880000);
    size_t need8 = 20880000ull + 2ull * 8 * 480000 * 4;
    int KZf = (ws_size >= need8) ? 8 : 1;
    float* part2 = part1 + (size_t)KZf * 480000;

    hipMemsetAsync(tsum, 0, M_TGT * sizeof(float), stream);
    resize_lin<<<dim3(M_TGT, 100), 256, 0, stream>>>(tmasks, T, tsum);
    probs_kernel<<<N_PRED, 64, 0, stream>>>(logits, probs);
    stats_kernel<<<N_PRED, 256, 0, stream>>>(pmasks, S, sump);
    gemm_fused<<<dim3(19, 7, KZf), 256, 0, stream>>>(pmasks, T, part1, part2, KDIM / KZf);
    combine_kernel<<<1875, 256, 0, stream>>>(part1, part2, S, sump, tsum, probs,
                                             pboxes, tboxes, tids, out, KZf);
  }
}

// Round 3
// 227.411 us; speedup vs baseline: 1.8775x; 1.5117x over previous
//
#include <hip/hip_runtime.h>
#include <cstdint>

#define N_PRED 1200
#define M_TGT  400
#define KDIM   25600   // 160*160
#define NCLS   81

typedef __attribute__((ext_vector_type(8))) short bf16x8;
typedef __attribute__((ext_vector_type(4))) float f32x4;

__device__ __forceinline__ ushort f2bf(float f) {
  union { float f; uint32_t u; } v; v.f = f;
  uint32_t u = v.u + 0x7fffu + ((v.u >> 16) & 1u);
  return (ushort)(u >> 16);
}

__device__ __forceinline__ void gll16(const void* g, void* l) {
  __builtin_amdgcn_global_load_lds(
      (const __attribute__((address_space(1))) void*)g,
      (__attribute__((address_space(3))) void*)l, 16, 0, 0);
}

// =====================================================================
// Convert pred_masks f32 -> X_swz (bf16 logits), P_swz (bf16 sigmoid), fused
// row stats. Fast-math: v_exp/v_log/v_rcp only (tolerance has ~4x headroom).
// Layout: X_swz[ntile][kt][row*8 + (q^(row&7))][8].
__global__ void convert_kernel(const float* __restrict__ pm, ushort* __restrict__ X,
                               ushort* __restrict__ P, float* __restrict__ S,
                               float* __restrict__ sump) {
  int n = blockIdx.x;            // 0..1279 (1200..1279 = zero pad rows)
  int t = threadIdx.x;
  int ntile = n >> 7, row = n & 127, r7 = row & 7;

  if (n >= N_PRED) {
    ushort4 z = {0, 0, 0, 0};
    for (int i = t; i < 3200; i += 256) {
      int kt = i >> 3, q = i & 7, slot = q ^ r7;
      size_t a = (((size_t)(ntile * 400 + kt)) << 13) + (size_t)(row * 8 + slot) * 8;
      *reinterpret_cast<ushort4*>(&X[a]) = z;
      *reinterpret_cast<ushort4*>(&X[a + 4]) = z;
      *reinterpret_cast<ushort4*>(&P[a]) = z;
      *reinterpret_cast<ushort4*>(&P[a + 4]) = z;
    }
    return;
  }

  const float4* src = reinterpret_cast<const float4*>(pm + (size_t)n * KDIM);
  float ssp = 0.f, sp = 0.f;
  for (int i = t; i < 3200; i += 256) {
    float4 f0 = src[i * 2];
    float4 f1 = src[i * 2 + 1];
    float xs[8] = {f0.x, f0.y, f0.z, f0.w, f1.x, f1.y, f1.z, f1.w};
    ushort xv[8], pv[8];
#pragma unroll
    for (int j = 0; j < 8; ++j) {
      float x = xs[j];
      float e = __expf(-fabsf(x));
      float op = 1.f + e;
      float inv = __builtin_amdgcn_rcpf(op);
      float sg = (x >= 0.f) ? inv : e * inv;
      sp += sg;
      ssp += fmaxf(x, 0.f) + __logf(op);     // softplus(x)
      xv[j] = f2bf(x);
      pv[j] = f2bf(sg);
    }
    int kt = i >> 3, q = i & 7, slot = q ^ r7;
    size_t a = (((size_t)(ntile * 400 + kt)) << 13) + (size_t)(row * 8 + slot) * 8;
    *reinterpret_cast<ushort4*>(&X[a])     = make_ushort4(xv[0], xv[1], xv[2], xv[3]);
    *reinterpret_cast<ushort4*>(&X[a + 4]) = make_ushort4(xv[4], xv[5], xv[6], xv[7]);
    *reinterpret_cast<ushort4*>(&P[a])     = make_ushort4(pv[0], pv[1], pv[2], pv[3]);
    *reinterpret_cast<ushort4*>(&P[a + 4]) = make_ushort4(pv[4], pv[5], pv[6], pv[7]);
  }
#pragma unroll
  for (int o = 32; o > 0; o >>= 1) {
    ssp += __shfl_down(ssp, o, 64);
    sp  += __shfl_down(sp, o, 64);
  }
  __shared__ float red[8];
  int wid = t >> 6;
  if ((t & 63) == 0) { red[wid] = ssp; red[4 + wid] = sp; }
  __syncthreads();
  if (t == 0) {
    S[n]    = -(red[0] + red[1] + red[2] + red[3]);
    sump[n] = red[4] + red[5] + red[6] + red[7];
  }
}

// =====================================================================
// Resize tgt_masks [400,256,256] -> T_swz [mtile(5)][kt(400)][row*8+(q^(row&7))][8]
// Block = (mask m, tile of 8 output rows). Separable: 16 input rows staged in
// LDS -> vertical pass (all 256 threads) -> horizontal pass (160 items) with
// swizzled 16B bf16 stores. One atomicAdd per block into tsum[m].
__global__ __launch_bounds__(256) void resize2(const float* __restrict__ tm,
                                               ushort* __restrict__ T,
                                               float* __restrict__ tsum) {
  __shared__ float rows[16][256];
  __shared__ float vbuf[8][256];

  int m = blockIdx.x, yt = blockIdx.y;  // yt 0..19
  int y0 = yt * 8;
  int t = threadIdx.x;
  int mtile = m / 80, trow = m % 80, tr7 = trow & 7;

  int jbase = (int)ceilf((y0 + 0.5f) * 1.6f - 2.1f);

  // stage 16 input rows (clamped), float4-coalesced
  const float* base = tm + (size_t)m * 65536;
  {
    int r = t >> 4;                 // 0..15
    int c0 = (t & 15) * 16;         // 16 floats = 4 float4 per thread
    int jr = min(max(jbase + r, 0), 255);
    const float4* src = reinterpret_cast<const float4*>(base + jr * 256 + c0);
#pragma unroll
    for (int i = 0; i < 4; ++i)
      *reinterpret_cast<float4*>(&rows[r][c0 + i * 4]) = src[i];
  }
  __syncthreads();

  // vertical: 8 output rows, thread t = column
#pragma unroll
  for (int yy = 0; yy < 8; ++yy) {
    int y = y0 + yy;
    float s = (y + 0.5f) * 1.6f - 0.5f;
    int j0 = (int)ceilf(s - 1.6f);
    float w[4]; float wsum = 0.f;
#pragma unroll
    for (int a = 0; a < 4; ++a) {
      int j = j0 + a;
      float wv = fmaxf(0.f, 1.f - fabsf((float)j - s) * 0.625f);
      if (j < 0 || j > 255) wv = 0.f;
      w[a] = wv; wsum += wv;
    }
    float winv = __builtin_amdgcn_rcpf(wsum);
    float acc = 0.f;
    int rbase = j0 - jbase;         // in [0,12]
#pragma unroll
    for (int a = 0; a < 4; ++a) acc += w[a] * rows[rbase + a][t];
    vbuf[yy][t] = acc * winv;
  }
  __syncthreads();

  // horizontal: 160 items (8 rows x 20 chunks of 8 outputs)
  float bsum = 0.f;
  if (t < 160) {
    int yy = t / 20, ch = t - yy * 20;
    float o[8];
#pragma unroll
    for (int j = 0; j < 8; ++j) {
      int x = ch * 8 + j;
      float sx = (x + 0.5f) * 1.6f - 0.5f;
      int jx0 = (int)ceilf(sx - 1.6f);
      float wsum = 0.f, h = 0.f;
#pragma unroll
      for (int b = 0; b < 4; ++b) {
        int jj = jx0 + b;
        float wv = fmaxf(0.f, 1.f - fabsf((float)jj - sx) * 0.625f);
        if (jj < 0 || jj > 255) wv = 0.f;
        wsum += wv;
        h += wv * vbuf[yy][min(max(jj, 0), 255)];
      }
      h *= __builtin_amdgcn_rcpf(wsum);
      o[j] = h; bsum += h;
    }
    int p0 = (y0 + yy) * 160 + ch * 8;
    int kt = p0 >> 6, q = (p0 >> 3) & 7, slot = q ^ tr7;
    size_t a = (size_t)(mtile * 400 + kt) * 5120 + (size_t)(trow * 8 + slot) * 8;
    *reinterpret_cast<ushort4*>(&T[a]) =
        make_ushort4(f2bf(o[0]), f2bf(o[1]), f2bf(o[2]), f2bf(o[3]));
    *reinterpret_cast<ushort4*>(&T[a + 4]) =
        make_ushort4(f2bf(o[4]), f2bf(o[5]), f2bf(o[6]), f2bf(o[7]));
  }
#pragma unroll
  for (int o2 = 32; o2 > 0; o2 >>= 1) bsum += __shfl_down(bsum, o2, 64);
  __shared__ float red[4];
  int wid = t >> 6;
  if ((t & 63) == 0) red[wid] = bsum;
  __syncthreads();
  if (t == 0) atomicAdd(&tsum[m], red[0] + red[1] + red[2] + red[3]);
}

// =====================================================================
// Dual GEMM from pre-swizzled bf16 operands. BM=128, BN=80, BK=64, 4 waves,
// global_load_lds(16B) staging from contiguous pre-swizzled blocks.
__global__ __launch_bounds__(256) void gemm_swz(
    const ushort* __restrict__ Xg, const ushort* __restrict__ Pg,
    const ushort* __restrict__ Tg, float* __restrict__ part1,
    float* __restrict__ part2, int steps) {
  __shared__ ushort lds[21504];   // X[0..8191] P[8192..16383] T[16384..21503]

  int bn = blockIdx.x, bm = blockIdx.y, kz = blockIdx.z;
  int t = threadIdx.x, lane = t & 63, w = t >> 6;
  int wbase = t & 0xFFC0;
  int kt0 = kz * steps;

  const ushort* srcX = Xg + (((size_t)(bn * 400 + kt0)) << 13);
  const ushort* srcP = Pg + (((size_t)(bn * 400 + kt0)) << 13);
  const ushort* srcT = Tg + (size_t)(bm * 400 + kt0) * 5120;

  int wr = w * 32, lrow = lane & 15, kq = lane >> 4;
  int r0 = wr + lrow, r1 = r0 + 16;
  int r07 = r0 & 7;

  f32x4 z = {0.f, 0.f, 0.f, 0.f};
  f32x4 acc1[2][5], acc2[2][5];
#pragma unroll
  for (int i = 0; i < 2; ++i)
#pragma unroll
    for (int j = 0; j < 5; ++j) { acc1[i][j] = z; acc2[i][j] = z; }

  for (int st = 0; st < steps; ++st) {
#pragma unroll
    for (int i = 0; i < 4; ++i)
      gll16(srcX + (size_t)(i * 256 + t) * 8, &lds[(i * 256 + wbase) * 8]);
#pragma unroll
    for (int i = 0; i < 4; ++i)
      gll16(srcP + (size_t)(i * 256 + t) * 8, &lds[8192 + (i * 256 + wbase) * 8]);
    gll16(srcT + (size_t)t * 8,         &lds[16384 + wbase * 8]);
    gll16(srcT + (size_t)(256 + t) * 8, &lds[16384 + (256 + wbase) * 8]);
    if (t < 128)
      gll16(srcT + (size_t)(512 + t) * 8, &lds[16384 + (512 + wbase) * 8]);
    __syncthreads();

#pragma unroll
    for (int h = 0; h < 2; ++h) {
      int q = h * 4 + kq;
      int sa = (q ^ r07) << 3;
      bf16x8 ax0 = *reinterpret_cast<const bf16x8*>(&lds[r0 * 64 + sa]);
      bf16x8 ax1 = *reinterpret_cast<const bf16x8*>(&lds[r1 * 64 + sa]);
      bf16x8 ap0 = *reinterpret_cast<const bf16x8*>(&lds[8192 + r0 * 64 + sa]);
      bf16x8 ap1 = *reinterpret_cast<const bf16x8*>(&lds[8192 + r1 * 64 + sa]);
      bf16x8 bt[5];
#pragma unroll
      for (int j = 0; j < 5; ++j) {
        int tr = j * 16 + lrow;
        bt[j] = *reinterpret_cast<const bf16x8*>(
            &lds[16384 + tr * 64 + ((q ^ (tr & 7)) << 3)]);
      }
#pragma unroll
      for (int j = 0; j < 5; ++j) {
        acc1[0][j] = __builtin_amdgcn_mfma_f32_16x16x32_bf16(ax0, bt[j], acc1[0][j], 0, 0, 0);
        acc1[1][j] = __builtin_amdgcn_mfma_f32_16x16x32_bf16(ax1, bt[j], acc1[1][j], 0, 0, 0);
        acc2[0][j] = __builtin_amdgcn_mfma_f32_16x16x32_bf16(ap0, bt[j], acc2[0][j], 0, 0, 0);
        acc2[1][j] = __builtin_amdgcn_mfma_f32_16x16x32_bf16(ap1, bt[j], acc2[1][j], 0, 0, 0);
      }
    }
    __syncthreads();
    srcX += 8192; srcP += 8192; srcT += 5120;
  }

  int rowb = (lane >> 4) * 4, col = lane & 15;
  int n0 = bn * 128 + wr;
#pragma unroll
  for (int i = 0; i < 2; ++i)
#pragma unroll
    for (int j = 0; j < 5; ++j)
#pragma unroll
      for (int rr = 0; rr < 4; ++rr) {
        int gn = n0 + i * 16 + rowb + rr;
        if (gn < N_PRED) {
          int gm = bm * 80 + j * 16 + col;
          size_t o = (size_t)kz * 480000 + (size_t)gn * 400 + gm;
          part1[o] = acc1[i][j][rr];
          part2[o] = acc2[i][j][rr];
        }
      }
}

// ---------------- softmax probs [1200,81] ----------------
__global__ void probs_kernel(const float* __restrict__ logits, float* __restrict__ probs) {
  int n = blockIdx.x;
  int l = threadIdx.x;
  const float* row = logits + n * NCLS;
  float v0 = row[l];
  bool has2 = (l + 64) < NCLS;
  float v1 = has2 ? row[l + 64] : -3.4e38f;
  float mx = fmaxf(v0, v1);
#pragma unroll
  for (int o = 1; o < 64; o <<= 1) mx = fmaxf(mx, __shfl_xor(mx, o, 64));
  float e0 = expf(v0 - mx);
  float e1 = has2 ? expf(v1 - mx) : 0.f;
  float sm = e0 + e1;
#pragma unroll
  for (int o = 1; o < 64; o <<= 1) sm += __shfl_xor(sm, o, 64);
  float inv = 1.f / sm;
  probs[n * NCLS + l] = e0 * inv;
  if (has2) probs[n * NCLS + l + 64] = e1 * inv;
}

// ---------------- final combine ----------------
__global__ void combine_kernel(const float* __restrict__ part1, const float* __restrict__ part2,
                               const float* __restrict__ S, const float* __restrict__ sump,
                               const float* __restrict__ tsum, const float* __restrict__ probs,
                               const float* __restrict__ pboxes, const float* __restrict__ tboxes,
                               const int* __restrict__ tids, float* __restrict__ out, int KZ) {
  int idx = blockIdx.x * 256 + threadIdx.x;
  int n = idx / M_TGT;
  int m = idx - n * M_TGT;

  float A1 = 0.f, A2 = 0.f;
  for (int kz = 0; kz < KZ; ++kz) {
    A1 += part1[(size_t)kz * 480000 + idx];
    A2 += part2[(size_t)kz * 480000 + idx];
  }
  float cm = -(A1 + S[n]) * (1.0f / (float)KDIM);
  float cd = 1.f - (2.f * A2 + 1e-5f) / (sump[n] + tsum[m] + 1e-5f);
  float cc = -probs[n * NCLS + tids[m]];

  float4 pb = reinterpret_cast<const float4*>(pboxes)[n];
  float4 tb = reinterpret_cast<const float4*>(tboxes)[m];
  float l1 = fabsf(pb.x - tb.x) + fabsf(pb.y - tb.y) + fabsf(pb.z - tb.z) + fabsf(pb.w - tb.w);
  float px1 = pb.x - 0.5f * pb.z, py1 = pb.y - 0.5f * pb.w;
  float px2 = pb.x + 0.5f * pb.z, py2 = pb.y + 0.5f * pb.w;
  float tx1 = tb.x - 0.5f * tb.z, ty1 = tb.y - 0.5f * tb.w;
  float tx2 = tb.x + 0.5f * tb.z, ty2 = tb.y + 0.5f * tb.w;
  float a1 = (px2 - px1) * (py2 - py1);
  float a2 = (tx2 - tx1) * (ty2 - ty1);
  float iw = fmaxf(fminf(px2, tx2) - fmaxf(px1, tx1), 0.f);
  float ih = fmaxf(fminf(py2, ty2) - fmaxf(py1, ty1), 0.f);
  float inter = iw * ih;
  float uni = a1 + a2 - inter;
  float iou = inter / uni;
  float ew = fmaxf(fmaxf(px2, tx2) - fminf(px1, tx1), 0.f);
  float eh = fmaxf(fmaxf(py2, ty2) - fminf(py1, ty1), 0.f);
  float ae = ew * eh;
  float giou = iou - (ae - uni) / ae;

  out[idx] = 5.f * l1 + 2.f * (-giou) + 2.f * cc + 5.f * cm + 5.f * cd;
}

// =====================================================================
// FALLBACK PATH (only if ws too small): round-1 style fused GEMM
// =====================================================================

__device__ __forceinline__ float sigf(float x) {
  return 1.f / (1.f + __expf(-x));
}

__global__ void resize_lin(const float* __restrict__ tm, ushort* __restrict__ T,
                           float* __restrict__ tsum) {
  int m = blockIdx.x;
  int p = blockIdx.y * 256 + threadIdx.x;
  int y = p / 160;
  int x = p - y * 160;
  float wy[4], wx[4];
  int jy0, jx0;
  {
    float s = (y + 0.5f) * 1.6f - 0.5f;
    jy0 = (int)ceilf(s - 1.6f);
    float ws = 0.f;
#pragma unroll
    for (int a = 0; a < 4; ++a) {
      int j = jy0 + a;
      float w = fmaxf(0.f, 1.f - fabsf((float)j - s) * 0.625f);
      if (j < 0 || j > 255) w = 0.f;
      wy[a] = w; ws += w;
    }
    float inv = 1.f / ws;
#pragma unroll
    for (int a = 0; a < 4; ++a) wy[a] *= inv;
  }
  {
    float s = (x + 0.5f) * 1.6f - 0.5f;
    jx0 = (int)ceilf(s - 1.6f);
    float ws = 0.f;
#pragma unroll
    for (int b = 0; b < 4; ++b) {
      int j = jx0 + b;
      float w = fmaxf(0.f, 1.f - fabsf((float)j - s) * 0.625f);
      if (j < 0 || j > 255) w = 0.f;
      wx[b] = w; ws += w;
    }
    float inv = 1.f / ws;
#pragma unroll
    for (int b = 0; b < 4; ++b) wx[b] *= inv;
  }
  const float* base = tm + (size_t)m * 65536;
  float acc = 0.f;
#pragma unroll
  for (int a = 0; a < 4; ++a) {
    int jy = min(max(jy0 + a, 0), 255);
    float wya = wy[a];
#pragma unroll
    for (int b = 0; b < 4; ++b) {
      int jx = min(max(jx0 + b, 0), 255);
      acc += wya * wx[b] * base[jy * 256 + jx];
    }
  }
  T[(size_t)m * KDIM + p] = f2bf(acc);
  float v = acc;
#pragma unroll
  for (int o = 32; o > 0; o >>= 1) v += __shfl_down(v, o, 64);
  __shared__ float red[4];
  int wid = threadIdx.x >> 6;
  if ((threadIdx.x & 63) == 0) red[wid] = v;
  __syncthreads();
  if (threadIdx.x == 0) atomicAdd(&tsum[m], red[0] + red[1] + red[2] + red[3]);
}

__global__ void stats_kernel(const float* __restrict__ pm, float* __restrict__ S,
                             float* __restrict__ sump) {
  int n = blockIdx.x;
  const float4* row = reinterpret_cast<const float4*>(pm + (size_t)n * KDIM);
  float ssp = 0.f, sp = 0.f;
  for (int i = threadIdx.x; i < KDIM / 4; i += 256) {
    float4 v = row[i];
    float xs[4] = {v.x, v.y, v.z, v.w};
#pragma unroll
    for (int j = 0; j < 4; ++j) {
      float x = xs[j];
      float e = __expf(-fabsf(x));
      float inv1pe = 1.f / (1.f + e);
      sp += (x >= 0.f) ? inv1pe : e * inv1pe;
      ssp += fmaxf(x, 0.f) + log1pf(e);
    }
  }
#pragma unroll
  for (int o = 32; o > 0; o >>= 1) {
    ssp += __shfl_down(ssp, o, 64);
    sp  += __shfl_down(sp, o, 64);
  }
  __shared__ float red[8];
  int wid = threadIdx.x >> 6;
  if ((threadIdx.x & 63) == 0) { red[wid] = ssp; red[4 + wid] = sp; }
  __syncthreads();
  if (threadIdx.x == 0) {
    S[n]    = -(red[0] + red[1] + red[2] + red[3]);
    sump[n] = red[4] + red[5] + red[6] + red[7];
  }
}

__device__ __forceinline__ bf16x8 load_frag_lin(const ushort* p) {
  union { ushort4 u[2]; bf16x8 f; } fr;
  fr.u[0] = *reinterpret_cast<const ushort4*>(p);
  fr.u[1] = *reinterpret_cast<const ushort4*>(p + 4);
  return fr.f;
}

__global__ __launch_bounds__(256) void gemm_fused(
    const float* __restrict__ pm, const ushort* __restrict__ T,
    float* __restrict__ part1, float* __restrict__ part2, int k_per) {
  __shared__ ushort Ax[64][40];
  __shared__ ushort Ap[64][40];
  __shared__ ushort Bs[64][40];
  int n0 = blockIdx.x * 64;
  int m0 = blockIdx.y * 64;
  int kz = blockIdx.z;
  int k_begin = kz * k_per;
  int t = threadIdx.x;
  int r = t >> 2;
  int q = t & 3;
  bool a_ok = (n0 + r) < N_PRED;
  bool b_ok = (m0 + r) < M_TGT;
  const float*  pA = pm + (size_t)(n0 + r) * KDIM + k_begin + q * 8;
  const ushort* pB = T  + (size_t)(m0 + r) * KDIM + k_begin + q * 8;
  int lane = t & 63;
  int w = t >> 6;
  int wr = (w >> 1) * 32;
  int wc = (w & 1) * 32;
  int lrow = lane & 15;
  int kc = (lane >> 4) * 8;
  f32x4 zero = {0.f, 0.f, 0.f, 0.f};
  f32x4 acc1[2][2] = {{zero, zero}, {zero, zero}};
  f32x4 acc2[2][2] = {{zero, zero}, {zero, zero}};
  int steps = k_per / 32;
  for (int kt = 0; kt < steps; ++kt) {
    __syncthreads();
    float4 f0 = {0.f,0.f,0.f,0.f}, f1 = {0.f,0.f,0.f,0.f};
    if (a_ok) {
      f0 = *reinterpret_cast<const float4*>(pA);
      f1 = *reinterpret_cast<const float4*>(pA + 4);
    }
    pA += 32;
    ushort4 xa, xb, pa, pb4;
    xa.x = f2bf(f0.x); xa.y = f2bf(f0.y); xa.z = f2bf(f0.z); xa.w = f2bf(f0.w);
    xb.x = f2bf(f1.x); xb.y = f2bf(f1.y); xb.z = f2bf(f1.z); xb.w = f2bf(f1.w);
    pa.x = f2bf(sigf(f0.x)); pa.y = f2bf(sigf(f0.y)); pa.z = f2bf(sigf(f0.z)); pa.w = f2bf(sigf(f0.w));
    pb4.x = f2bf(sigf(f1.x)); pb4.y = f2bf(sigf(f1.y)); pb4.z = f2bf(sigf(f1.z)); pb4.w = f2bf(sigf(f1.w));
    *reinterpret_cast<ushort4*>(&Ax[r][q * 8])     = xa;
    *reinterpret_cast<ushort4*>(&Ax[r][q * 8 + 4]) = xb;
    *reinterpret_cast<ushort4*>(&Ap[r][q * 8])     = pa;
    *reinterpret_cast<ushort4*>(&Ap[r][q * 8 + 4]) = pb4;
    union { uint4 u; ushort4 s[2]; } bv;
    bv.u = make_uint4(0, 0, 0, 0);
    if (b_ok) bv.u = *reinterpret_cast<const uint4*>(pB);
    pB += 32;
    *reinterpret_cast<ushort4*>(&Bs[r][q * 8])     = bv.s[0];
    *reinterpret_cast<ushort4*>(&Bs[r][q * 8 + 4]) = bv.s[1];
    __syncthreads();
    bf16x8 ax[2], ap[2], bb[2];
#pragma unroll
    for (int i = 0; i < 2; ++i) {
      ax[i] = load_frag_lin(&Ax[wr + i * 16 + lrow][kc]);
      ap[i] = load_frag_lin(&Ap[wr + i * 16 + lrow][kc]);
      bb[i] = load_frag_lin(&Bs[wc + i * 16 + lrow][kc]);
    }
#pragma unroll
    for (int i = 0; i < 2; ++i)
#pragma unroll
      for (int j = 0; j < 2; ++j) {
        acc1[i][j] = __builtin_amdgcn_mfma_f32_16x16x32_bf16(ax[i], bb[j], acc1[i][j], 0, 0, 0);
        acc2[i][j] = __builtin_amdgcn_mfma_f32_16x16x32_bf16(ap[i], bb[j], acc2[i][j], 0, 0, 0);
      }
  }
  int rowb = (lane >> 4) * 4;
  int col = lane & 15;
#pragma unroll
  for (int i = 0; i < 2; ++i)
#pragma unroll
    for (int j = 0; j < 2; ++j)
#pragma unroll
      for (int rr = 0; rr < 4; ++rr) {
        int gn = n0 + wr + i * 16 + rowb + rr;
        int gm = m0 + wc + j * 16 + col;
        if (gn < N_PRED && gm < M_TGT) {
          size_t o = (size_t)kz * 480000 + (size_t)gn * 400 + gm;
          part1[o] = acc1[i][j][rr];
          part2[o] = acc2[i][j][rr];
        }
      }
}

// =====================================================================

extern "C" void kernel_launch(void* const* d_in, const int* in_sizes, int n_in,
                              void* d_out, int out_size, void* d_ws, size_t ws_size,
                              hipStream_t stream) {
  const float* logits = (const float*)d_in[0];
  const float* pboxes = (const float*)d_in[1];
  const float* pmasks = (const float*)d_in[2];
  const float* tboxes = (const float*)d_in[3];
  const float* tmasks = (const float*)d_in[4];
  const int*   tids   = (const int*)d_in[5];
  float* out = (float*)d_out;
  char* ws = (char*)d_ws;

  const size_t offX = 0;
  const size_t offP = 65536000;
  const size_t offT = 131072000;
  const size_t offProbs = 151552000;
  const size_t offS = 151940800;
  const size_t offSump = 151945600;
  const size_t offTsum = 151950400;
  const size_t offParts = 151952000;

  int KZ = 0;
  if      (ws_size >= offParts + 2ull * 16 * 480000 * 4) KZ = 16;
  else if (ws_size >= offParts + 2ull * 8  * 480000 * 4) KZ = 8;
  else if (ws_size >= offParts + 2ull * 4  * 480000 * 4) KZ = 4;
  else if (ws_size >= offParts + 2ull * 2  * 480000 * 4) KZ = 2;

  if (KZ > 0) {
    ushort* Xg   = (ushort*)(ws + offX);
    ushort* Pg   = (ushort*)(ws + offP);
    ushort* Tg   = (ushort*)(ws + offT);
    float* probs = (float*)(ws + offProbs);
    float* S     = (float*)(ws + offS);
    float* sump  = (float*)(ws + offSump);
    float* tsum  = (float*)(ws + offTsum);
    float* part1 = (float*)(ws + offParts);
    float* part2 = part1 + (size_t)KZ * 480000;

    hipMemsetAsync(tsum, 0, M_TGT * sizeof(float), stream);
    convert_kernel<<<1280, 256, 0, stream>>>(pmasks, Xg, Pg, S, sump);
    resize2<<<dim3(M_TGT, 20), 256, 0, stream>>>(tmasks, Tg, tsum);
    probs_kernel<<<N_PRED, 64, 0, stream>>>(logits, probs);
    gemm_swz<<<dim3(10, 5, KZ), 256, 0, stream>>>(Xg, Pg, Tg, part1, part2, 400 / KZ);
    combine_kernel<<<1875, 256, 0, stream>>>(part1, part2, S, sump, tsum, probs,
                                             pboxes, tboxes, tids, out, KZ);
  } else {
    ushort* T     = (ushort*)ws;
    float*  probs = (float*)(ws + 20480000);
    float*  S     = (float*)(ws + 20868800);
    float*  sump  = (float*)(ws + 20873600);
    float*  tsum  = (float*)(ws + 20878400);
    float*  part1 = (float*)(ws + 20880000);
    size_t need8 = 20880000ull + 2ull * 8 * 480000 * 4;
    int KZf = (ws_size >= need8) ? 8 : 1;
    float* part2 = part1 + (size_t)KZf * 480000;

    hipMemsetAsync(tsum, 0, M_TGT * sizeof(float), stream);
    resize_lin<<<dim3(M_TGT, 100), 256, 0, stream>>>(tmasks, T, tsum);
    probs_kernel<<<N_PRED, 64, 0, stream>>>(logits, probs);
    stats_kernel<<<N_PRED, 256, 0, stream>>>(pmasks, S, sump);
    gemm_fused<<<dim3(19, 7, KZf), 256, 0, stream>>>(pmasks, T, part1, part2, KDIM / KZf);
    combine_kernel<<<1875, 256, 0, stream>>>(part1, part2, S, sump, tsum, probs,
                                             pboxes, tboxes, tids, out, KZf);
  }
}